// Round 7
// baseline (431.497 us; speedup 1.0000x reference)
//
#include <hip/hip_runtime.h>
#include <hip/hip_bf16.h>

using bf16x8 = __attribute__((ext_vector_type(8))) __bf16;
using fx4    = __attribute__((ext_vector_type(4))) float;
using us4    = __attribute__((ext_vector_type(4))) unsigned short;
using us8    = __attribute__((ext_vector_type(8))) unsigned short;

__device__ __forceinline__ float b2f(unsigned short u) {
    unsigned int x = ((unsigned int)u) << 16;
    return __builtin_bit_cast(float, x);
}
__device__ __forceinline__ unsigned short f2b(float f) {
    __hip_bfloat16 h = __float2bfloat16(f);
    return __builtin_bit_cast(unsigned short, h);
}
__device__ __forceinline__ float logsigmoidf(float z) {
    return fminf(z, 0.0f) - log1pf(expf(-fabsf(z)));
}

// async 16B/lane global->LDS (dest = wave-uniform base + lane*16)
__device__ __forceinline__ void gl_lds16(const unsigned short* g, unsigned short* l) {
    __builtin_amdgcn_global_load_lds(
        (const __attribute__((address_space(1))) void*)g,
        (__attribute__((address_space(3))) void*)l, 16, 0, 0);
}

// 64-col bf16 LDS tile, 8-elem chunks XOR-swizzled by row&7 (2-way alias = free)
__device__ __forceinline__ bf16x8 frag64(const unsigned short* base, int row, int cq) {
    return *reinterpret_cast<const bf16x8*>(base + row * 64 + (((cq ^ (row & 7)) << 3)));
}
__device__ __forceinline__ int sw_idx(int row, int col) {
    return row * 64 + ((((col >> 3) ^ (row & 7)) << 3)) + (col & 7);
}

// ---------------------------------------------------------------------------
// dtype detect (flag=1 -> fp32 inputs)
// ---------------------------------------------------------------------------
__global__ __launch_bounds__(256) void detect_kernel(
    const unsigned int* __restrict__ x, int* __restrict__ flag)
{
    __shared__ int bad[256];
    const int t = threadIdx.x;
    int b = 0;
#pragma unroll
    for (int i = 0; i < 16; ++i) {
        unsigned int w = x[t * 16 + i];
        float v = b2f((unsigned short)(w & 0xFFFFu));
        if (!(fabsf(v) < 1.0e6f)) b = 1;
    }
    bad[t] = b;
    __syncthreads();
    for (int s = 128; s > 0; s >>= 1) {
        if (t < s) bad[t] |= bad[t + s];
        __syncthreads();
    }
    if (t == 0) flag[0] = bad[0];
}

// ---------------------------------------------------------------------------
// fused convert: all 10 inputs -> bf16 in one launch (round-0 block-indexed
// form: 24627 blocks, max TLP; grid-stride variant regressed ~+5-8 us).
// ---------------------------------------------------------------------------
struct CvtArgs {
    const void* src[10];
    unsigned short* dst[10];
};

__global__ __launch_bounds__(256) void convert_all_kernel(
    CvtArgs a, const int* __restrict__ flag)
{
    const int pref[11] = {0, 8192, 10240, 12288, 12320, 12336, 12337,
                          16433, 20529, 20531, 24627};
    const int blk = blockIdx.x;
    int s = 0;
#pragma unroll
    for (int i = 1; i < 10; ++i) s += (blk >= pref[i]) ? 1 : 0;
    const int i0 = (blk - pref[s]) * 1024 + threadIdx.x * 4;
    if (*flag) {
        const float* sp = (const float*)a.src[s];
        fx4 v = *reinterpret_cast<const fx4*>(sp + i0);
        us4 r;
#pragma unroll
        for (int e = 0; e < 4; ++e) r[e] = f2b(v[e]);
        *reinterpret_cast<us4*>(a.dst[s] + i0) = r;
    } else {
        const unsigned short* sp = (const unsigned short*)a.src[s];
        *reinterpret_cast<us4*>(a.dst[s] + i0) =
            *reinterpret_cast<const us4*>(sp + i0);
    }
}

// ---------------------------------------------------------------------------
// fused 3-output GEMM: x @ [Wq;Wk;Wv;Wg]^T, m97 structure, 256x128 tile,
// 512 threads = 8 waves (4M x 2N).  vs 128^2-m97: -24% staging bytes/FLOP,
// 48KB LDS -> still 3 blocks/CU but 24 waves/CU, grid 48x16 = 768 = 3x256
// (all blocks co-resident, no multi-round tail).
// ---------------------------------------------------------------------------
struct Seg3 {
    unsigned short* C0;   // qk
    unsigned short* C1;   // v
    unsigned short* C2;   // g (silu(x@Wg^T + bg))
    const unsigned short* bias2;
};

__global__ __launch_bounds__(512) void gemm_fused3_kernel(
    const unsigned short* __restrict__ A, const unsigned short* __restrict__ W,
    Seg3 segs, float scale_k)
{
    const int K = 2048;
    __shared__ __align__(16) unsigned short As[256 * 64];   // 32KB
    __shared__ __align__(16) unsigned short Bs[128 * 64];   // 16KB

    const int tid  = threadIdx.x;
    const int lane = tid & 63, wid = tid >> 6;              // wid in [0,8)
    const int quad = lane >> 4, l15 = lane & 15;
    const int wm = (wid & 3) * 64, wn = (wid >> 2) * 64;    // 4M x 2N waves
    const int m0 = blockIdx.y * 256, n0 = blockIdx.x * 128;

    fx4 acc[4][4];
#pragma unroll
    for (int i = 0; i < 4; ++i)
#pragma unroll
        for (int j = 0; j < 4; ++j) acc[i][j] = fx4{0.f, 0.f, 0.f, 0.f};

    const int srow = lane >> 3;
    const int g8   = ((lane & 7) ^ srow) * 8;
    const int c8   = (lane & 7) * 8;
    const unsigned short* Ab = A + (size_t)m0 * K;
    const unsigned short* Wb = W + (size_t)n0 * K;

    for (int k0 = 0; k0 < K; k0 += 64) {
#pragma unroll
        for (int p = 0; p < 4; ++p) {
            const int row = (wid * 4 + p) * 8 + srow;       // 0..255
            gl_lds16(Ab + (size_t)row * K + k0 + g8, As + row * 64 + c8);
        }
#pragma unroll
        for (int p = 0; p < 2; ++p) {
            const int row = (wid * 2 + p) * 8 + srow;       // 0..127
            gl_lds16(Wb + (size_t)row * K + k0 + g8, Bs + row * 64 + c8);
        }
        __syncthreads();
#pragma unroll
        for (int ks = 0; ks < 2; ++ks) {
            const int cq = quad + ks * 4;
            bf16x8 af[4], bfr[4];
#pragma unroll
            for (int mt = 0; mt < 4; ++mt) af[mt] = frag64(As, wm + mt * 16 + l15, cq);
#pragma unroll
            for (int nt = 0; nt < 4; ++nt) bfr[nt] = frag64(Bs, wn + nt * 16 + l15, cq);
#pragma unroll
            for (int mt = 0; mt < 4; ++mt)
#pragma unroll
                for (int nt = 0; nt < 4; ++nt)
                    acc[mt][nt] = __builtin_amdgcn_mfma_f32_16x16x32_bf16(
                        af[mt], bfr[nt], acc[mt][nt], 0, 0, 0);
        }
        __syncthreads();
    }

    const int segi = n0 >> 11;  // 128-col tile lies fully inside one segment
    unsigned short* Cs = (segi == 0) ? segs.C0 : ((segi == 1) ? segs.C1 : segs.C2);
#pragma unroll
    for (int nt = 0; nt < 4; ++nt) {
        const int ncl = (n0 & 2047) + wn + nt * 16 + l15;   // col within segment
        const float av = (segi == 0 && ncl >= 1024) ? scale_k : 1.0f;
        const float bv = (segi == 2) ? b2f(segs.bias2[ncl]) : 0.0f;
#pragma unroll
        for (int mt = 0; mt < 4; ++mt) {
#pragma unroll
            for (int r = 0; r < 4; ++r) {
                const int mrow = m0 + wm + mt * 16 + quad * 4 + r;
                float val = acc[mt][nt][r] * av + bv;
                if (segi == 2) val = val / (1.0f + __expf(-val));
                Cs[(size_t)mrow * 2048 + ncl] = f2b(val);
            }
        }
    }
}

// ---------------------------------------------------------------------------
// GEMM for the final y @ Wo^T; same 256x128 / 512-thread m97 structure.
// out bf16 or fp32 via *oflag.
// ---------------------------------------------------------------------------
__global__ __launch_bounds__(512) void gemm_bt_kernel(
    const unsigned short* __restrict__ A, const unsigned short* __restrict__ W,
    unsigned short* __restrict__ C, int M, int N, int K,
    const int* __restrict__ oflag)
{
    __shared__ __align__(16) unsigned short As[256 * 64];
    __shared__ __align__(16) unsigned short Bs[128 * 64];

    const int tid  = threadIdx.x;
    const int lane = tid & 63, wid = tid >> 6;
    const int quad = lane >> 4, l15 = lane & 15;
    const int wm = (wid & 3) * 64, wn = (wid >> 2) * 64;
    const int m0 = blockIdx.y * 256, n0 = blockIdx.x * 128;

    fx4 acc[4][4];
#pragma unroll
    for (int i = 0; i < 4; ++i)
#pragma unroll
        for (int j = 0; j < 4; ++j) acc[i][j] = fx4{0.f, 0.f, 0.f, 0.f};

    const int srow = lane >> 3;
    const int g8   = ((lane & 7) ^ srow) * 8;
    const int c8   = (lane & 7) * 8;
    const unsigned short* Ab = A + (size_t)m0 * K;
    const unsigned short* Wb = W + (size_t)n0 * K;

    for (int k0 = 0; k0 < K; k0 += 64) {
#pragma unroll
        for (int p = 0; p < 4; ++p) {
            const int row = (wid * 4 + p) * 8 + srow;
            gl_lds16(Ab + (size_t)row * K + k0 + g8, As + row * 64 + c8);
        }
#pragma unroll
        for (int p = 0; p < 2; ++p) {
            const int row = (wid * 2 + p) * 8 + srow;
            gl_lds16(Wb + (size_t)row * K + k0 + g8, Bs + row * 64 + c8);
        }
        __syncthreads();
#pragma unroll
        for (int ks = 0; ks < 2; ++ks) {
            const int cq = quad + ks * 4;
            bf16x8 af[4], bfr[4];
#pragma unroll
            for (int mt = 0; mt < 4; ++mt) af[mt] = frag64(As, wm + mt * 16 + l15, cq);
#pragma unroll
            for (int nt = 0; nt < 4; ++nt) bfr[nt] = frag64(Bs, wn + nt * 16 + l15, cq);
#pragma unroll
            for (int mt = 0; mt < 4; ++mt)
#pragma unroll
                for (int nt = 0; nt < 4; ++nt)
                    acc[mt][nt] = __builtin_amdgcn_mfma_f32_16x16x32_bf16(
                        af[mt], bfr[nt], acc[mt][nt], 0, 0, 0);
        }
        __syncthreads();
    }

    const int f32out = oflag ? *oflag : 0;
#pragma unroll
    for (int nt = 0; nt < 4; ++nt) {
        const int ncol = n0 + wn + nt * 16 + l15;
#pragma unroll
        for (int mt = 0; mt < 4; ++mt) {
#pragma unroll
            for (int r = 0; r < 4; ++r) {
                const int mrow = m0 + wm + mt * 16 + quad * 4 + r;
                float val = acc[mt][nt][r];
                const size_t idx = (size_t)mrow * N + ncol;
                if (f32out) ((float*)C)[idx] = val;
                else        C[idx] = f2b(val);
            }
        }
    }
}

// ---------------------------------------------------------------------------
// gate1: LDS-tree reduction (16 DS-writes + 16 strided reads + 4 shfl).
// block = one row m.  Ag <- logsigmoid(kg)/16  (not yet cumsummed)
// ---------------------------------------------------------------------------
__global__ __launch_bounds__(256) void gate1_kernel(
    const unsigned short* __restrict__ x, const unsigned short* __restrict__ Wkg1,
    const unsigned short* __restrict__ Wkg2, const unsigned short* __restrict__ bkg2,
    float* __restrict__ Ag)
{
    __shared__ float part[16][257];
    __shared__ float kgrow[16];
    const int m = blockIdx.x;
    const int tid = threadIdx.x;

    us8 xv = *reinterpret_cast<const us8*>(x + (size_t)m * 2048 + tid * 8);
    float xr[8];
#pragma unroll
    for (int e = 0; e < 8; ++e) xr[e] = b2f(xv[e]);

#pragma unroll
    for (int n = 0; n < 16; ++n) {
        us8 wv = *reinterpret_cast<const us8*>(Wkg1 + (size_t)n * 2048 + tid * 8);
        float s = 0.f;
#pragma unroll
        for (int e = 0; e < 8; ++e) s += xr[e] * b2f(wv[e]);
        part[n][tid] = s;
    }
    __syncthreads();
    {
        const int n = tid >> 4, i = tid & 15;   // 16 threads per n, within-wave
        float s = 0.f;
#pragma unroll
        for (int k2 = 0; k2 < 16; ++k2) s += part[n][i + k2 * 16];
#pragma unroll
        for (int off = 1; off < 16; off <<= 1) s += __shfl_xor(s, off, 64);
        if (i == 0) kgrow[n] = s;
    }
    __syncthreads();
    float kr[16];
#pragma unroll
    for (int j = 0; j < 16; ++j) kr[j] = kgrow[j];

    const int b = m >> 11, l = m & 2047;
    const int c0 = tid * 4;
    const int h = c0 >> 6, d0 = c0 & 63;
    fx4 gv;
#pragma unroll
    for (int qi = 0; qi < 4; ++qi) {
        const int c = c0 + qi;
        us8 w0 = *reinterpret_cast<const us8*>(Wkg2 + (size_t)c * 16);
        us8 w1 = *reinterpret_cast<const us8*>(Wkg2 + (size_t)c * 16 + 8);
        float z = b2f(bkg2[c]);
#pragma unroll
        for (int j = 0; j < 8; ++j) z += kr[j] * b2f(w0[j]) + kr[8 + j] * b2f(w1[j]);
        gv[qi] = logsigmoidf(z) * 0.0625f;
    }
    *reinterpret_cast<fx4*>(Ag + ((size_t)(b * 16 + h) * 2048 + l) * 64 + d0) = gv;
}

// ---------------------------------------------------------------------------
// gate2: in-chunk (64) inclusive cumsum along t, in place.
// ---------------------------------------------------------------------------
__global__ __launch_bounds__(256) void gate2_kernel(float* __restrict__ Ag)
{
    const int gidx = blockIdx.x * 256 + threadIdx.x;   // 65536
    const int d = gidx & 63, ch = (gidx >> 6) & 31, bh = gidx >> 11;
    float* p = Ag + ((size_t)bh * 2048 + ch * 64) * 64 + d;
    float acc = 0.f;
#pragma unroll 8
    for (int t = 0; t < 64; ++t) {
        acc += p[(size_t)t * 64];
        p[(size_t)t * 64] = acc;
    }
}

// ---------------------------------------------------------------------------
// pass1 (MFMA): T^T[j][d] = sum_s v[s,j] * k[s,d]*exp(A63[d]-A[s][d])
// ---------------------------------------------------------------------------
__global__ __launch_bounds__(256) void pass1_kernel(
    const unsigned short* __restrict__ k, int kstr,
    const unsigned short* __restrict__ v,
    const float* __restrict__ Ag, float* __restrict__ Tc)
{
    __shared__ __align__(16) unsigned short kT[64 * 64];   // [d][s]
    __shared__ __align__(16) unsigned short vT[128 * 64];  // [j][s]

    const int blk = blockIdx.x;
    const int ch = blk & 31, bh = blk >> 5;
    const int b = bh >> 4, h = bh & 15;
    const int tid = threadIdx.x;
    const int lane = tid & 63, w = tid >> 6;
    const int quad = lane >> 4, l15 = lane & 15;

    const float* Abase = Ag + ((size_t)bh * 2048 + ch * 64) * 64;
    const unsigned short* kbase = k + ((size_t)(b * 2048 + ch * 64)) * kstr + h * 64;
    const unsigned short* vbase = v + ((size_t)(b * 2048 + ch * 64)) * 2048 + h * 128;

    {
        const int s = tid >> 2, d0 = (tid & 3) * 16;
        float av[16], a63[16];
        *(fx4*)(av)      = *(const fx4*)(Abase + (size_t)s * 64 + d0);
        *(fx4*)(av + 4)  = *(const fx4*)(Abase + (size_t)s * 64 + d0 + 4);
        *(fx4*)(av + 8)  = *(const fx4*)(Abase + (size_t)s * 64 + d0 + 8);
        *(fx4*)(av + 12) = *(const fx4*)(Abase + (size_t)s * 64 + d0 + 12);
        *(fx4*)(a63)      = *(const fx4*)(Abase + (size_t)63 * 64 + d0);
        *(fx4*)(a63 + 4)  = *(const fx4*)(Abase + (size_t)63 * 64 + d0 + 4);
        *(fx4*)(a63 + 8)  = *(const fx4*)(Abase + (size_t)63 * 64 + d0 + 8);
        *(fx4*)(a63 + 12) = *(const fx4*)(Abase + (size_t)63 * 64 + d0 + 12);
        us8 k0v = *(const us8*)(kbase + (size_t)s * kstr + d0);
        us8 k1v = *(const us8*)(kbase + (size_t)s * kstr + d0 + 8);
#pragma unroll
        for (int e = 0; e < 8; ++e) {
            kT[sw_idx(d0 + e, s)]     = f2b(b2f(k0v[e]) * __expf(a63[e] - av[e]));
            kT[sw_idx(d0 + 8 + e, s)] = f2b(b2f(k1v[e]) * __expf(a63[8 + e] - av[8 + e]));
        }
    }
    {
        const int s = tid >> 2, j0 = (tid & 3) * 32;
#pragma unroll
        for (int g2 = 0; g2 < 4; ++g2) {
            us8 vv = *(const us8*)(vbase + (size_t)s * 2048 + j0 + g2 * 8);
#pragma unroll
            for (int e = 0; e < 8; ++e) vT[sw_idx(j0 + g2 * 8 + e, s)] = vv[e];
        }
    }
    __syncthreads();

    bf16x8 bk[4][2];
#pragma unroll
    for (int nt = 0; nt < 4; ++nt) {
        bk[nt][0] = frag64(kT, nt * 16 + l15, quad);
        bk[nt][1] = frag64(kT, nt * 16 + l15, quad + 4);
    }
    fx4 acc[2][4];
#pragma unroll
    for (int mi = 0; mi < 2; ++mi)
#pragma unroll
        for (int nt = 0; nt < 4; ++nt) acc[mi][nt] = fx4{0.f, 0.f, 0.f, 0.f};
#pragma unroll
    for (int mi = 0; mi < 2; ++mi) {
        const int mrow = (w * 2 + mi) * 16 + l15;
        bf16x8 av0 = frag64(vT, mrow, quad);
        bf16x8 av1 = frag64(vT, mrow, quad + 4);
#pragma unroll
        for (int nt = 0; nt < 4; ++nt) {
            acc[mi][nt] = __builtin_amdgcn_mfma_f32_16x16x32_bf16(av0, bk[nt][0], acc[mi][nt], 0, 0, 0);
            acc[mi][nt] = __builtin_amdgcn_mfma_f32_16x16x32_bf16(av1, bk[nt][1], acc[mi][nt], 0, 0, 0);
        }
    }
    float* tb = Tc + (size_t)blk * 8192;
#pragma unroll
    for (int mi = 0; mi < 2; ++mi)
#pragma unroll
        for (int nt = 0; nt < 4; ++nt)
#pragma unroll
            for (int r = 0; r < 4; ++r) {
                const int j = (w * 2 + mi) * 16 + quad * 4 + r;
                const int d = nt * 16 + l15;
                tb[(size_t)j * 64 + d] = acc[mi][nt][r];
            }
}

// ---------------------------------------------------------------------------
// combine: 256 blocks, one fx4 chain per thread over the 32 chunks.
// TS holds T^T [j][d] fp32 on entry; on exit each 16B fx4 slot holds the
// PACKED bf16 {hi[4], lo[4]} of S_start (hi = f2b(S), lo = f2b(S - hi)).
// In-place safe: each thread reads its own fx4 slot before overwriting it.
// ---------------------------------------------------------------------------
__global__ __launch_bounds__(256) void combine_kernel(
    float* __restrict__ TS, const float* __restrict__ Ag)
{
    const int blk = blockIdx.x;       // bh*8 + js
    const int js = blk & 7, bh = blk >> 3;
    const int tid = threadIdx.x;
    const int j = js * 16 + (tid >> 4), d0 = (tid & 15) * 4;
    fx4 S = fx4{0.f, 0.f, 0.f, 0.f};
    const float* Abase = Ag + (size_t)bh * 2048 * 64;
    for (int c = 0; c < 32; ++c) {
        float* p = TS + ((size_t)(bh * 32 + c)) * 8192 + (size_t)j * 64 + d0;
        fx4 t = *(const fx4*)p;
        us8 pk;
#pragma unroll
        for (int e = 0; e < 4; ++e) {
            pk[e]     = f2b(S[e]);
            pk[4 + e] = f2b(S[e] - b2f(pk[e]));
        }
        *(us8*)p = pk;
        fx4 a = *(const fx4*)(Abase + ((size_t)c * 64 + 63) * 64 + d0);
#pragma unroll
        for (int e = 0; e < 4; ++e) S[e] = S[e] * __expf(a[e]) + t[e];
    }
}

// ---------------------------------------------------------------------------
// pass2 (MFMA): P = tri(Q~K~^T); O = Q~@S^T(hi/lo pre-packed) + P@V; LN;
// silu-gate; y.
// ---------------------------------------------------------------------------
__global__ __launch_bounds__(256) void pass2_kernel(
    const unsigned short* __restrict__ q, const unsigned short* __restrict__ k,
    int qkstr,
    const unsigned short* __restrict__ v, const float* __restrict__ Ag,
    const float* __restrict__ Sst, const unsigned short* __restrict__ sg,
    unsigned short* __restrict__ y)
{
    __shared__ __align__(16) unsigned short qs[64 * 64];    // q~ [t][d]
    __shared__ __align__(16) unsigned short ksh[64 * 64];   // k~ [s][d]
    __shared__ __align__(16) unsigned short vT[128 * 64];   // v^T [j][s]
    __shared__ __align__(16) unsigned short Pb[64 * 64];    // P [t][s] bf16
    __shared__ __align__(16) unsigned short Ob[64 * 144];   // normalized O [t][j]

    const int blk = blockIdx.x;
    const int ch = blk & 31, bh = blk >> 5;
    const int b = bh >> 4, h = bh & 15;
    const int tid = threadIdx.x;
    const int lane = tid & 63, w = tid >> 6;
    const int quad = lane >> 4, l15 = lane & 15;

    const float* Abase = Ag + ((size_t)bh * 2048 + ch * 64) * 64;
    const unsigned short* qbase = q + ((size_t)(b * 2048 + ch * 64)) * qkstr + h * 64;
    const unsigned short* kbase = k + ((size_t)(b * 2048 + ch * 64)) * qkstr + h * 64;
    const unsigned short* vbase = v + ((size_t)(b * 2048 + ch * 64)) * 2048 + h * 128;

    {
        const int t = tid >> 2, d0 = (tid & 3) * 16;
        float av[16];
        *(fx4*)(av)      = *(const fx4*)(Abase + (size_t)t * 64 + d0);
        *(fx4*)(av + 4)  = *(const fx4*)(Abase + (size_t)t * 64 + d0 + 4);
        *(fx4*)(av + 8)  = *(const fx4*)(Abase + (size_t)t * 64 + d0 + 8);
        *(fx4*)(av + 12) = *(const fx4*)(Abase + (size_t)t * 64 + d0 + 12);
        us8 q0 = *(const us8*)(qbase + (size_t)t * qkstr + d0);
        us8 q1 = *(const us8*)(qbase + (size_t)t * qkstr + d0 + 8);
        us8 k0 = *(const us8*)(kbase + (size_t)t * qkstr + d0);
        us8 k1 = *(const us8*)(kbase + (size_t)t * qkstr + d0 + 8);
        us8 qo0, qo1, ko0, ko1;
#pragma unroll
        for (int e = 0; e < 8; ++e) {
            float e0 = __expf(av[e]),     n0 = __expf(-av[e]);
            float e1 = __expf(av[8 + e]), n1 = __expf(-av[8 + e]);
            qo0[e] = f2b(b2f(q0[e]) * e0);
            qo1[e] = f2b(b2f(q1[e]) * e1);
            ko0[e] = f2b(b2f(k0[e]) * n0);
            ko1[e] = f2b(b2f(k1[e]) * n1);
        }
        const int c0 = d0 >> 3, t7 = t & 7;
        *(us8*)(qs  + t * 64 + ((c0 ^ t7) << 3))       = qo0;
        *(us8*)(qs  + t * 64 + (((c0 + 1) ^ t7) << 3)) = qo1;
        *(us8*)(ksh + t * 64 + ((c0 ^ t7) << 3))       = ko0;
        *(us8*)(ksh + t * 64 + (((c0 + 1) ^ t7) << 3)) = ko1;
    }
    {
        const int s = tid >> 2, j0 = (tid & 3) * 32;
#pragma unroll
        for (int g2 = 0; g2 < 4; ++g2) {
            us8 vv = *(const us8*)(vbase + (size_t)s * 2048 + j0 + g2 * 8);
#pragma unroll
            for (int e = 0; e < 8; ++e) vT[sw_idx(j0 + g2 * 8 + e, s)] = vv[e];
        }
    }
    __syncthreads();

    bf16x8 aQ0 = frag64(qs, w * 16 + l15, quad);
    bf16x8 aQ1 = frag64(qs, w * 16 + l15, quad + 4);
    fx4 accP[4];
#pragma unroll
    for (int nt = 0; nt < 4; ++nt) accP[nt] = fx4{0.f, 0.f, 0.f, 0.f};
#pragma unroll
    for (int nt = 0; nt < 4; ++nt) {
        bf16x8 bK0 = frag64(ksh, nt * 16 + l15, quad);
        bf16x8 bK1 = frag64(ksh, nt * 16 + l15, quad + 4);
        accP[nt] = __builtin_amdgcn_mfma_f32_16x16x32_bf16(aQ0, bK0, accP[nt], 0, 0, 0);
        accP[nt] = __builtin_amdgcn_mfma_f32_16x16x32_bf16(aQ1, bK1, accP[nt], 0, 0, 0);
    }
#pragma unroll
    for (int nt = 0; nt < 4; ++nt)
#pragma unroll
        for (int r = 0; r < 4; ++r) {
            const int t = w * 16 + quad * 4 + r;
            const int s = nt * 16 + l15;
            Pb[sw_idx(t, s)] = f2b((s <= t) ? accP[nt][r] : 0.0f);
        }
    __syncthreads();

    bf16x8 aP0 = frag64(Pb, w * 16 + l15, quad);
    bf16x8 aP1 = frag64(Pb, w * 16 + l15, quad + 4);
    const unsigned short* SP = (const unsigned short*)(Sst + (size_t)blk * 8192);
    fx4 accO[8];
#pragma unroll
    for (int nt = 0; nt < 8; ++nt) accO[nt] = fx4{0.f, 0.f, 0.f, 0.f};
#pragma unroll
    for (int nt = 0; nt < 8; ++nt) {
        const int j = nt * 16 + l15;
        bf16x8 bV0 = frag64(vT, j, quad);
        bf16x8 bV1 = frag64(vT, j, quad + 4);
        // packed {hi[4],lo[4]} slots written by combine.
        // group d=quad*8: ga/gb ; group d=32+quad*8: +32 floats = +64 u16.
        const unsigned short* sb = SP + (size_t)(j * 64 + quad * 8) * 2;
        us8 ga = *(const us8*)(sb);          // elems quad*8+0..3  {hi4,lo4}
        us8 gb = *(const us8*)(sb + 8);      // elems quad*8+4..7
        us8 gc = *(const us8*)(sb + 64);     // elems 32+quad*8+0..3
        us8 gd = *(const us8*)(sb + 72);     // elems 32+quad*8+4..7
        us8 hi0u = __builtin_shufflevector(ga, gb, 0, 1, 2, 3, 8, 9, 10, 11);
        us8 lo0u = __builtin_shufflevector(ga, gb, 4, 5, 6, 7, 12, 13, 14, 15);
        us8 hi1u = __builtin_shufflevector(gc, gd, 0, 1, 2, 3, 8, 9, 10, 11);
        us8 lo1u = __builtin_shufflevector(gc, gd, 4, 5, 6, 7, 12, 13, 14, 15);
        bf16x8 hi0 = __builtin_bit_cast(bf16x8, hi0u);
        bf16x8 lo0 = __builtin_bit_cast(bf16x8, lo0u);
        bf16x8 hi1 = __builtin_bit_cast(bf16x8, hi1u);
        bf16x8 lo1 = __builtin_bit_cast(bf16x8, lo1u);
        accO[nt] = __builtin_amdgcn_mfma_f32_16x16x32_bf16(aP0, bV0, accO[nt], 0, 0, 0);
        accO[nt] = __builtin_amdgcn_mfma_f32_16x16x32_bf16(aP1, bV1, accO[nt], 0, 0, 0);
        accO[nt] = __builtin_amdgcn_mfma_f32_16x16x32_bf16(aQ0, hi0, accO[nt], 0, 0, 0);
        accO[nt] = __builtin_amdgcn_mfma_f32_16x16x32_bf16(aQ1, hi1, accO[nt], 0, 0, 0);
        accO[nt] = __builtin_amdgcn_mfma_f32_16x16x32_bf16(aQ0, lo0, accO[nt], 0, 0, 0);
        accO[nt] = __builtin_amdgcn_mfma_f32_16x16x32_bf16(aQ1, lo1, accO[nt], 0, 0, 0);
    }

    float sum1[4] = {0.f, 0.f, 0.f, 0.f}, sum2[4] = {0.f, 0.f, 0.f, 0.f};
#pragma unroll
    for (int nt = 0; nt < 8; ++nt)
#pragma unroll
        for (int r = 0; r < 4; ++r) {
            float ov = accO[nt][r];
            sum1[r] += ov;
            sum2[r] += ov * ov;
        }
#pragma unroll
    for (int m = 1; m < 16; m <<= 1)
#pragma unroll
        for (int r = 0; r < 4; ++r) {
            sum1[r] += __shfl_xor(sum1[r], m, 64);
            sum2[r] += __shfl_xor(sum2[r], m, 64);
        }
    float mu[4], inv[4];
#pragma unroll
    for (int r = 0; r < 4; ++r) {
        mu[r] = sum1[r] * (1.0f / 128.0f);
        float var = sum2[r] * (1.0f / 128.0f) - mu[r] * mu[r];
        inv[r] = rsqrtf(var + 1e-5f);
    }
#pragma unroll
    for (int nt = 0; nt < 8; ++nt)
#pragma unroll
        for (int r = 0; r < 4; ++r) {
            const int t = w * 16 + quad * 4 + r;
            Ob[t * 144 + nt * 16 + l15] = f2b((accO[nt][r] - mu[r]) * inv[r]);
        }
    __syncthreads();

    {
        const int t2 = tid >> 2, jg = (tid & 3) * 32;
        const size_t obase = ((size_t)(b * 2048 + ch * 64 + t2)) * 2048 + h * 128 + jg;
#pragma unroll
        for (int g2 = 0; g2 < 4; ++g2) {
            us8 ob = *(const us8*)(Ob + t2 * 144 + jg + g2 * 8);
            us8 gv = *(const us8*)(sg + obase + g2 * 8);
            us8 ov;
#pragma unroll
            for (int e = 0; e < 8; ++e) ov[e] = f2b(b2f(gv[e]) * b2f(ob[e]));
            *(us8*)(y + obase + g2 * 8) = ov;
        }
    }
}

// ---------------------------------------------------------------------------
extern "C" void kernel_launch(void* const* d_in, const int* in_sizes, int n_in,
                              void* d_out, int out_size, void* d_ws, size_t ws_size,
                              hipStream_t stream)
{
    unsigned short* out = (unsigned short*)d_out;

    char* ws = (char*)d_ws;
    size_t off = 0;
    auto alloc = [&](size_t bytes) -> void* {
        void* p = ws + off;
        off += (bytes + 255) & ~(size_t)255;
        return p;
    };
    unsigned short* xb    = (unsigned short*)alloc((size_t)4096 * 2048 * 2);
    unsigned short* Wbig  = (unsigned short*)alloc((size_t)6144 * 2048 * 2); // [Wq;Wk;Wv;Wg]
    unsigned short* Wkg1b = (unsigned short*)alloc((size_t)16 * 2048 * 2);
    unsigned short* Wkg2b = (unsigned short*)alloc((size_t)1024 * 16 * 2);
    unsigned short* bkg2b = (unsigned short*)alloc((size_t)1024 * 2);
    unsigned short* bgb   = (unsigned short*)alloc((size_t)2048 * 2);
    unsigned short* Wob   = (unsigned short*)alloc((size_t)2048 * 2048 * 2);
    unsigned short* qkb  = (unsigned short*)alloc((size_t)4096 * 2048 * 2);  // q|k
    unsigned short* vb   = (unsigned short*)alloc((size_t)4096 * 2048 * 2);
    unsigned short* sgb  = (unsigned short*)alloc((size_t)4096 * 2048 * 2);
    unsigned short* yb   = (unsigned short*)alloc((size_t)4096 * 2048 * 2);
    float*          Agb  = (float*)alloc((size_t)4096 * 1024 * 4);
    float*          TS   = (float*)alloc((size_t)1024 * 8192 * 4);
    int*            flag = (int*)alloc(256);

    detect_kernel<<<1, 256, 0, stream>>>((const unsigned int*)d_in[0], flag);

    CvtArgs ca;
    ca.src[0] = d_in[0]; ca.dst[0] = xb;
    ca.src[1] = d_in[1]; ca.dst[1] = Wbig;                         // Wq
    ca.src[2] = d_in[2]; ca.dst[2] = Wbig + (size_t)1024 * 2048;   // Wk
    ca.src[3] = d_in[3]; ca.dst[3] = Wkg1b;
    ca.src[4] = d_in[4]; ca.dst[4] = Wkg2b;
    ca.src[5] = d_in[5]; ca.dst[5] = bkg2b;
    ca.src[6] = d_in[6]; ca.dst[6] = Wbig + (size_t)2048 * 2048;   // Wv
    ca.src[7] = d_in[7]; ca.dst[7] = Wbig + (size_t)4096 * 2048;   // Wg
    ca.src[8] = d_in[8]; ca.dst[8] = bgb;
    ca.src[9] = d_in[9]; ca.dst[9] = Wob;
    convert_all_kernel<<<24627, 256, 0, stream>>>(ca, flag);

    const float SCALE = 0.08838834764831845f;  // 128**-0.5

    Seg3 segs;
    segs.C0 = qkb; segs.C1 = vb; segs.C2 = sgb; segs.bias2 = bgb;
    gemm_fused3_kernel<<<dim3(48, 16), 512, 0, stream>>>(xb, Wbig, segs, SCALE);

    gate1_kernel<<<4096, 256, 0, stream>>>(xb, Wkg1b, Wkg2b, bkg2b, Agb);
    gate2_kernel<<<256, 256, 0, stream>>>(Agb);
    pass1_kernel<<<1024, 256, 0, stream>>>(qkb + 1024, 2048, vb, Agb, TS);
    combine_kernel<<<256, 256, 0, stream>>>(TS, Agb);
    pass2_kernel<<<1024, 256, 0, stream>>>(qkb, qkb + 1024, 2048, vb, Agb, TS, sgb, yb);
    gemm_bt_kernel<<<dim3(16, 16), 512, 0, stream>>>(yb, Wob, out, 4096, 2048, 2048, flag);
}

// Round 8
// 400.580 us; speedup vs baseline: 1.0772x; 1.0772x over previous
//
#include <hip/hip_runtime.h>
#include <hip/hip_bf16.h>

using bf16x8 = __attribute__((ext_vector_type(8))) __bf16;
using fx4    = __attribute__((ext_vector_type(4))) float;
using us4    = __attribute__((ext_vector_type(4))) unsigned short;
using us8    = __attribute__((ext_vector_type(8))) unsigned short;

__device__ __forceinline__ float b2f(unsigned short u) {
    unsigned int x = ((unsigned int)u) << 16;
    return __builtin_bit_cast(float, x);
}
__device__ __forceinline__ unsigned short f2b(float f) {
    __hip_bfloat16 h = __float2bfloat16(f);
    return __builtin_bit_cast(unsigned short, h);
}
__device__ __forceinline__ float logsigmoidf(float z) {
    return fminf(z, 0.0f) - log1pf(expf(-fabsf(z)));
}

// async 16B/lane global->LDS (dest = wave-uniform base + lane*16)
__device__ __forceinline__ void gl_lds16(const unsigned short* g, unsigned short* l) {
    __builtin_amdgcn_global_load_lds(
        (const __attribute__((address_space(1))) void*)g,
        (__attribute__((address_space(3))) void*)l, 16, 0, 0);
}

// 64-col bf16 LDS tile, 8-elem chunks XOR-swizzled by row&7 (2-way alias = free)
__device__ __forceinline__ bf16x8 frag64(const unsigned short* base, int row, int cq) {
    return *reinterpret_cast<const bf16x8*>(base + row * 64 + (((cq ^ (row & 7)) << 3)));
}
__device__ __forceinline__ int sw_idx(int row, int col) {
    return row * 64 + ((((col >> 3) ^ (row & 7)) << 3)) + (col & 7);
}

// ---------------------------------------------------------------------------
// dtype detect (flag=1 -> fp32 inputs)
// ---------------------------------------------------------------------------
__global__ __launch_bounds__(256) void detect_kernel(
    const unsigned int* __restrict__ x, int* __restrict__ flag)
{
    __shared__ int bad[256];
    const int t = threadIdx.x;
    int b = 0;
#pragma unroll
    for (int i = 0; i < 16; ++i) {
        unsigned int w = x[t * 16 + i];
        float v = b2f((unsigned short)(w & 0xFFFFu));
        if (!(fabsf(v) < 1.0e6f)) b = 1;
    }
    bad[t] = b;
    __syncthreads();
    for (int s = 128; s > 0; s >>= 1) {
        if (t < s) bad[t] |= bad[t + s];
        __syncthreads();
    }
    if (t == 0) flag[0] = bad[0];
}

// ---------------------------------------------------------------------------
// fused convert: all 10 inputs -> bf16 in one launch (block-indexed, max TLP).
// ---------------------------------------------------------------------------
struct CvtArgs {
    const void* src[10];
    unsigned short* dst[10];
};

__global__ __launch_bounds__(256) void convert_all_kernel(
    CvtArgs a, const int* __restrict__ flag)
{
    const int pref[11] = {0, 8192, 10240, 12288, 12320, 12336, 12337,
                          16433, 20529, 20531, 24627};
    const int blk = blockIdx.x;
    int s = 0;
#pragma unroll
    for (int i = 1; i < 10; ++i) s += (blk >= pref[i]) ? 1 : 0;
    const int i0 = (blk - pref[s]) * 1024 + threadIdx.x * 4;
    if (*flag) {
        const float* sp = (const float*)a.src[s];
        fx4 v = *reinterpret_cast<const fx4*>(sp + i0);
        us4 r;
#pragma unroll
        for (int e = 0; e < 4; ++e) r[e] = f2b(v[e]);
        *reinterpret_cast<us4*>(a.dst[s] + i0) = r;
    } else {
        const unsigned short* sp = (const unsigned short*)a.src[s];
        *reinterpret_cast<us4*>(a.dst[s] + i0) =
            *reinterpret_cast<const us4*>(sp + i0);
    }
}

// ---------------------------------------------------------------------------
// Kernel A: qk|v segments (N=4096), 256x256-tile 8-phase schedule (r6
// verified, 982 TF steady).  grid 16x16 = 256 blocks = EXACTLY 1 round at
// 1 block/CU -> no grid-quantization tail (r6's 140us was 384 blocks = 1.5
// rounds of the same 70us round).
// ---------------------------------------------------------------------------
struct Seg3 {
    unsigned short* C0;   // qk
    unsigned short* C1;   // v
    unsigned short* C2;   // g (unused in kernel A)
    const unsigned short* bias2;
};

__global__ __launch_bounds__(512, 2) void gemm_fused3_kernel(
    const unsigned short* __restrict__ A, const unsigned short* __restrict__ W,
    Seg3 segs, float scale_k)
{
    __shared__ __align__(16) unsigned short As[2 * 256 * 64];       // 64KB
    __shared__ __align__(16) unsigned short Bs[2 * 2 * 128 * 64];   // 64KB

    const int NT = 32, K = 2048;
    const int tid  = threadIdx.x;
    const int lane = tid & 63, wid = tid >> 6;
    const int quad = lane >> 4, l15 = lane & 15;
    const int wr = wid >> 2, wc = wid & 3;
    const int m0 = blockIdx.y * 256, n0 = blockIdx.x * 256;

    const unsigned short* Ab = A + (size_t)m0 * K;
    const unsigned short* Wb = W + (size_t)n0 * K;

    // ---- staging geometry (pre-swizzled source, linear LDS dest) ----
    const int sx = ((tid & 7) ^ ((tid >> 3) & 7)) * 8;
    const unsigned short* pA[2][2];   // [mh][j]
    const unsigned short* pB[2][2];   // [nh][j]
#pragma unroll
    for (int mh = 0; mh < 2; ++mh)
#pragma unroll
        for (int j = 0; j < 2; ++j)
            pA[mh][j] = Ab + (size_t)(j * 128 + mh * 64 + (tid >> 3)) * K + sx;
#pragma unroll
    for (int nh = 0; nh < 2; ++nh)
#pragma unroll
        for (int j = 0; j < 2; ++j)
            pB[nh][j] = Wb + (size_t)((j * 2 + (tid >> 8)) * 64 + nh * 32 +
                                      ((tid >> 3) & 31)) * K + sx;

    fx4 acc[8][4];
#pragma unroll
    for (int i = 0; i < 8; ++i)
#pragma unroll
        for (int j = 0; j < 4; ++j) acc[i][j] = fx4{0.f, 0.f, 0.f, 0.f};

    auto stageA = [&](int mh, int tt) {
#pragma unroll
        for (int j = 0; j < 2; ++j)
            gl_lds16(pA[mh][j] + tt * 64,
                     As + (tt & 1) * 16384 + (j * 128 + mh * 64) * 64 + tid * 8);
    };
    auto stageB = [&](int nh, int tt) {
#pragma unroll
        for (int j = 0; j < 2; ++j)
            gl_lds16(pB[nh][j] + tt * 64,
                     Bs + (tt & 1) * 16384 + nh * 8192 + j * 4096 + tid * 8);
    };

    // ---- fragment read geometry ----
    bf16x8 afr[4][2], bfr[2][2];
    const int x7 = l15 & 7;
    const int cswz0 = (quad ^ x7) << 3;
    const int cswz1 = ((quad + 4) ^ x7) << 3;
    int arow[4], brow[2];
#pragma unroll
    for (int mt = 0; mt < 4; ++mt) arow[mt] = (wr * 128 + mt * 16 + l15) * 64;
#pragma unroll
    for (int nt = 0; nt < 2; ++nt) brow[nt] = (wc * 32 + nt * 16 + l15) * 64;

    auto ldA = [&](int s, int mh) {
        const unsigned short* base = As + s * 16384 + mh * 4096;
#pragma unroll
        for (int mt = 0; mt < 4; ++mt) {
            afr[mt][0] = *(const bf16x8*)(base + arow[mt] + cswz0);
            afr[mt][1] = *(const bf16x8*)(base + arow[mt] + cswz1);
        }
    };
    auto ldB = [&](int s, int nh) {
        const unsigned short* base = Bs + s * 16384 + nh * 8192;
#pragma unroll
        for (int nt = 0; nt < 2; ++nt) {
            bfr[nt][0] = *(const bf16x8*)(base + brow[nt] + cswz0);
            bfr[nt][1] = *(const bf16x8*)(base + brow[nt] + cswz1);
        }
    };
    auto mma = [&](int mh, int nh) {
        __builtin_amdgcn_s_setprio(1);
#pragma unroll
        for (int mt = 0; mt < 4; ++mt)
#pragma unroll
            for (int nt = 0; nt < 2; ++nt) {
                acc[mh * 4 + mt][nh * 2 + nt] = __builtin_amdgcn_mfma_f32_16x16x32_bf16(
                    afr[mt][0], bfr[nt][0], acc[mh * 4 + mt][nh * 2 + nt], 0, 0, 0);
                acc[mh * 4 + mt][nh * 2 + nt] = __builtin_amdgcn_mfma_f32_16x16x32_bf16(
                    afr[mt][1], bfr[nt][1], acc[mh * 4 + mt][nh * 2 + nt], 0, 0, 0);
            }
        __builtin_amdgcn_s_setprio(0);
    };

    // ---- prologue: stage tile 0 fully + A0,B0 of tile 1; certify tile 0 ----
    stageA(0, 0); stageB(0, 0); stageA(1, 0); stageB(1, 0);
    stageA(0, 1); stageB(0, 1);
    asm volatile("s_waitcnt vmcnt(4)" ::: "memory");
    asm volatile("s_barrier" ::: "memory");

    for (int t = 0; t < NT; ++t) {
        const int s = t & 1;
        // ---- phase 0 (mh0, nh0) ----
        ldA(s, 0); ldB(s, 0);
        if (t + 1 < NT) stageA(1, t + 1);
        asm volatile("s_barrier" ::: "memory");
        __builtin_amdgcn_sched_barrier(0);
        mma(0, 0);
        asm volatile("s_barrier" ::: "memory");
        // ---- phase 1 (mh0, nh1) ----
        ldB(s, 1);
        if (t + 1 < NT) stageB(1, t + 1);
        asm volatile("s_barrier" ::: "memory");
        __builtin_amdgcn_sched_barrier(0);
        mma(0, 1);
        asm volatile("s_barrier" ::: "memory");
        // ---- phase 2 (mh1, nh0) ----
        ldA(s, 1); ldB(s, 0);
        if (t + 2 < NT) stageA(0, t + 2);
        asm volatile("s_barrier" ::: "memory");
        __builtin_amdgcn_sched_barrier(0);
        mma(1, 0);
        asm volatile("s_barrier" ::: "memory");
        // ---- phase 3 (mh1, nh1) ----
        ldB(s, 1);
        if (t + 2 < NT) stageB(0, t + 2);
        asm volatile("s_barrier" ::: "memory");
        __builtin_amdgcn_sched_barrier(0);
        mma(1, 1);
        // certify tile t+1 (all 4 halves) before its p0 reads:
        if (t < NT - 2)       asm volatile("s_waitcnt vmcnt(4)" ::: "memory");
        else if (t == NT - 2) asm volatile("s_waitcnt vmcnt(0)" ::: "memory");
        asm volatile("s_barrier" ::: "memory");
    }

    // ---- epilogue (segi 0: qk w/ k-scale; segi 1: v) ----
    const int segi = n0 >> 11;
    unsigned short* Cs = (segi == 0) ? segs.C0 : segs.C1;
#pragma unroll
    for (int j = 0; j < 4; ++j) {
        const int ncl = (n0 & 2047) + wc * 64 + j * 16 + l15;
        const float av = (segi == 0 && ncl >= 1024) ? scale_k : 1.0f;
#pragma unroll
        for (int i = 0; i < 8; ++i) {
#pragma unroll
            for (int r = 0; r < 4; ++r) {
                const int mrow = m0 + wr * 128 + i * 16 + quad * 4 + r;
                Cs[(size_t)mrow * 2048 + ncl] = f2b(acc[i][j][r] * av);
            }
        }
    }
}

// ---------------------------------------------------------------------------
// Kernel B: g segment (N=2048), m97-128^2 structure (round-0 verified; 512
// blocks at 3/CU, all co-resident).  out = silu(x@Wg^T + bg).
// ---------------------------------------------------------------------------
__global__ __launch_bounds__(256) void gemm_g_kernel(
    const unsigned short* __restrict__ A, const unsigned short* __restrict__ W,
    unsigned short* __restrict__ C, const unsigned short* __restrict__ bias)
{
    const int K = 2048;
    __shared__ __align__(16) unsigned short As[128 * 64];
    __shared__ __align__(16) unsigned short Bs[128 * 64];

    const int tid  = threadIdx.x;
    const int lane = tid & 63, wid = tid >> 6;
    const int quad = lane >> 4, l15 = lane & 15;
    const int wm = (wid & 1) * 64, wn = (wid >> 1) * 64;
    const int m0 = blockIdx.y * 128, n0 = blockIdx.x * 128;

    fx4 acc[4][4];
#pragma unroll
    for (int i = 0; i < 4; ++i)
#pragma unroll
        for (int j = 0; j < 4; ++j) acc[i][j] = fx4{0.f, 0.f, 0.f, 0.f};

    const int srow = lane >> 3;
    const int g8   = ((lane & 7) ^ srow) * 8;
    const int c8   = (lane & 7) * 8;
    const unsigned short* Ab = A + (size_t)m0 * K;
    const unsigned short* Wb = W + (size_t)(4096 + n0) * K;   // g-segment rows

    for (int k0 = 0; k0 < K; k0 += 64) {
#pragma unroll
        for (int p = 0; p < 4; ++p) {
            const int la  = wid * 4 + p;
            const int row = la * 8 + srow;
            gl_lds16(Ab + (size_t)row * K + k0 + g8, As + row * 64 + c8);
            gl_lds16(Wb + (size_t)row * K + k0 + g8, Bs + row * 64 + c8);
        }
        __syncthreads();
#pragma unroll
        for (int ks = 0; ks < 2; ++ks) {
            const int cq = quad + ks * 4;
            bf16x8 af[4], bfr[4];
#pragma unroll
            for (int mt = 0; mt < 4; ++mt) af[mt] = frag64(As, wm + mt * 16 + l15, cq);
#pragma unroll
            for (int nt = 0; nt < 4; ++nt) bfr[nt] = frag64(Bs, wn + nt * 16 + l15, cq);
#pragma unroll
            for (int mt = 0; mt < 4; ++mt)
#pragma unroll
                for (int nt = 0; nt < 4; ++nt)
                    acc[mt][nt] = __builtin_amdgcn_mfma_f32_16x16x32_bf16(
                        af[mt], bfr[nt], acc[mt][nt], 0, 0, 0);
        }
        __syncthreads();
    }

#pragma unroll
    for (int nt = 0; nt < 4; ++nt) {
        const int ncl = n0 + wn + nt * 16 + l15;
        const float bv = b2f(bias[ncl]);
#pragma unroll
        for (int mt = 0; mt < 4; ++mt) {
#pragma unroll
            for (int r = 0; r < 4; ++r) {
                const int mrow = m0 + wm + mt * 16 + quad * 4 + r;
                float val = acc[mt][nt][r] + bv;
                val = val / (1.0f + __expf(-val));
                C[(size_t)mrow * 2048 + ncl] = f2b(val);
            }
        }
    }
}

// ---------------------------------------------------------------------------
// GEMM (m97 structure, round-0 verified) for the final y @ Wo^T.
// ---------------------------------------------------------------------------
__global__ __launch_bounds__(256) void gemm_bt_kernel(
    const unsigned short* __restrict__ A, const unsigned short* __restrict__ W,
    unsigned short* __restrict__ C, int M, int N, int K,
    const int* __restrict__ oflag)
{
    __shared__ __align__(16) unsigned short As[128 * 64];
    __shared__ __align__(16) unsigned short Bs[128 * 64];

    const int tid  = threadIdx.x;
    const int lane = tid & 63, wid = tid >> 6;
    const int quad = lane >> 4, l15 = lane & 15;
    const int wm = (wid & 1) * 64, wn = (wid >> 1) * 64;
    const int m0 = blockIdx.y * 128, n0 = blockIdx.x * 128;

    fx4 acc[4][4];
#pragma unroll
    for (int i = 0; i < 4; ++i)
#pragma unroll
        for (int j = 0; j < 4; ++j) acc[i][j] = fx4{0.f, 0.f, 0.f, 0.f};

    const int srow = lane >> 3;
    const int g8   = ((lane & 7) ^ srow) * 8;
    const int c8   = (lane & 7) * 8;
    const unsigned short* Ab = A + (size_t)m0 * K;
    const unsigned short* Wb = W + (size_t)n0 * K;

    for (int k0 = 0; k0 < K; k0 += 64) {
#pragma unroll
        for (int p = 0; p < 4; ++p) {
            const int la  = wid * 4 + p;
            const int row = la * 8 + srow;
            gl_lds16(Ab + (size_t)row * K + k0 + g8, As + row * 64 + c8);
            gl_lds16(Wb + (size_t)row * K + k0 + g8, Bs + row * 64 + c8);
        }
        __syncthreads();
#pragma unroll
        for (int ks = 0; ks < 2; ++ks) {
            const int cq = quad + ks * 4;
            bf16x8 af[4], bfr[4];
#pragma unroll
            for (int mt = 0; mt < 4; ++mt) af[mt] = frag64(As, wm + mt * 16 + l15, cq);
#pragma unroll
            for (int nt = 0; nt < 4; ++nt) bfr[nt] = frag64(Bs, wn + nt * 16 + l15, cq);
#pragma unroll
            for (int mt = 0; mt < 4; ++mt)
#pragma unroll
                for (int nt = 0; nt < 4; ++nt)
                    acc[mt][nt] = __builtin_amdgcn_mfma_f32_16x16x32_bf16(
                        af[mt], bfr[nt], acc[mt][nt], 0, 0, 0);
        }
        __syncthreads();
    }

    const int f32out = oflag ? *oflag : 0;
#pragma unroll
    for (int nt = 0; nt < 4; ++nt) {
        const int ncol = n0 + wn + nt * 16 + l15;
#pragma unroll
        for (int mt = 0; mt < 4; ++mt) {
#pragma unroll
            for (int r = 0; r < 4; ++r) {
                const int mrow = m0 + wm + mt * 16 + quad * 4 + r;
                float val = acc[mt][nt][r];
                const size_t idx = (size_t)mrow * N + ncol;
                if (f32out) ((float*)C)[idx] = val;
                else        C[idx] = f2b(val);
            }
        }
    }
}

// ---------------------------------------------------------------------------
// gate1: LDS-tree reduction (16 DS-writes + 16 strided reads + 4 shfl).
// block = one row m.  Ag <- logsigmoid(kg)/16  (not yet cumsummed)
// ---------------------------------------------------------------------------
__global__ __launch_bounds__(256) void gate1_kernel(
    const unsigned short* __restrict__ x, const unsigned short* __restrict__ Wkg1,
    const unsigned short* __restrict__ Wkg2, const unsigned short* __restrict__ bkg2,
    float* __restrict__ Ag)
{
    __shared__ float part[16][257];
    __shared__ float kgrow[16];
    const int m = blockIdx.x;
    const int tid = threadIdx.x;

    us8 xv = *reinterpret_cast<const us8*>(x + (size_t)m * 2048 + tid * 8);
    float xr[8];
#pragma unroll
    for (int e = 0; e < 8; ++e) xr[e] = b2f(xv[e]);

#pragma unroll
    for (int n = 0; n < 16; ++n) {
        us8 wv = *reinterpret_cast<const us8*>(Wkg1 + (size_t)n * 2048 + tid * 8);
        float s = 0.f;
#pragma unroll
        for (int e = 0; e < 8; ++e) s += xr[e] * b2f(wv[e]);
        part[n][tid] = s;
    }
    __syncthreads();
    {
        const int n = tid >> 4, i = tid & 15;
        float s = 0.f;
#pragma unroll
        for (int k2 = 0; k2 < 16; ++k2) s += part[n][i + k2 * 16];
#pragma unroll
        for (int off = 1; off < 16; off <<= 1) s += __shfl_xor(s, off, 64);
        if (i == 0) kgrow[n] = s;
    }
    __syncthreads();
    float kr[16];
#pragma unroll
    for (int j = 0; j < 16; ++j) kr[j] = kgrow[j];

    const int b = m >> 11, l = m & 2047;
    const int c0 = tid * 4;
    const int h = c0 >> 6, d0 = c0 & 63;
    fx4 gv;
#pragma unroll
    for (int qi = 0; qi < 4; ++qi) {
        const int c = c0 + qi;
        us8 w0 = *reinterpret_cast<const us8*>(Wkg2 + (size_t)c * 16);
        us8 w1 = *reinterpret_cast<const us8*>(Wkg2 + (size_t)c * 16 + 8);
        float z = b2f(bkg2[c]);
#pragma unroll
        for (int j = 0; j < 8; ++j) z += kr[j] * b2f(w0[j]) + kr[8 + j] * b2f(w1[j]);
        gv[qi] = logsigmoidf(z) * 0.0625f;
    }
    *reinterpret_cast<fx4*>(Ag + ((size_t)(b * 16 + h) * 2048 + l) * 64 + d0) = gv;
}

// ---------------------------------------------------------------------------
// gate2: in-chunk (64) inclusive cumsum along t, in place.
// ---------------------------------------------------------------------------
__global__ __launch_bounds__(256) void gate2_kernel(float* __restrict__ Ag)
{
    const int gidx = blockIdx.x * 256 + threadIdx.x;   // 65536
    const int d = gidx & 63, ch = (gidx >> 6) & 31, bh = gidx >> 11;
    float* p = Ag + ((size_t)bh * 2048 + ch * 64) * 64 + d;
    float acc = 0.f;
#pragma unroll 8
    for (int t = 0; t < 64; ++t) {
        acc += p[(size_t)t * 64];
        p[(size_t)t * 64] = acc;
    }
}

// ---------------------------------------------------------------------------
// pass1 (MFMA): T^T[j][d] = sum_s v[s,j] * k[s,d]*exp(A63[d]-A[s][d])
// ---------------------------------------------------------------------------
__global__ __launch_bounds__(256) void pass1_kernel(
    const unsigned short* __restrict__ k, int kstr,
    const unsigned short* __restrict__ v,
    const float* __restrict__ Ag, float* __restrict__ Tc)
{
    __shared__ __align__(16) unsigned short kT[64 * 64];   // [d][s]
    __shared__ __align__(16) unsigned short vT[128 * 64];  // [j][s]

    const int blk = blockIdx.x;
    const int ch = blk & 31, bh = blk >> 5;
    const int b = bh >> 4, h = bh & 15;
    const int tid = threadIdx.x;
    const int lane = tid & 63, w = tid >> 6;
    const int quad = lane >> 4, l15 = lane & 15;

    const float* Abase = Ag + ((size_t)bh * 2048 + ch * 64) * 64;
    const unsigned short* kbase = k + ((size_t)(b * 2048 + ch * 64)) * kstr + h * 64;
    const unsigned short* vbase = v + ((size_t)(b * 2048 + ch * 64)) * 2048 + h * 128;

    {
        const int s = tid >> 2, d0 = (tid & 3) * 16;
        float av[16], a63[16];
        *(fx4*)(av)      = *(const fx4*)(Abase + (size_t)s * 64 + d0);
        *(fx4*)(av + 4)  = *(const fx4*)(Abase + (size_t)s * 64 + d0 + 4);
        *(fx4*)(av + 8)  = *(const fx4*)(Abase + (size_t)s * 64 + d0 + 8);
        *(fx4*)(av + 12) = *(const fx4*)(Abase + (size_t)s * 64 + d0 + 12);
        *(fx4*)(a63)      = *(const fx4*)(Abase + (size_t)63 * 64 + d0);
        *(fx4*)(a63 + 4)  = *(const fx4*)(Abase + (size_t)63 * 64 + d0 + 4);
        *(fx4*)(a63 + 8)  = *(const fx4*)(Abase + (size_t)63 * 64 + d0 + 8);
        *(fx4*)(a63 + 12) = *(const fx4*)(Abase + (size_t)63 * 64 + d0 + 12);
        us8 k0v = *(const us8*)(kbase + (size_t)s * kstr + d0);
        us8 k1v = *(const us8*)(kbase + (size_t)s * kstr + d0 + 8);
#pragma unroll
        for (int e = 0; e < 8; ++e) {
            kT[sw_idx(d0 + e, s)]     = f2b(b2f(k0v[e]) * __expf(a63[e] - av[e]));
            kT[sw_idx(d0 + 8 + e, s)] = f2b(b2f(k1v[e]) * __expf(a63[8 + e] - av[8 + e]));
        }
    }
    {
        const int s = tid >> 2, j0 = (tid & 3) * 32;
#pragma unroll
        for (int g2 = 0; g2 < 4; ++g2) {
            us8 vv = *(const us8*)(vbase + (size_t)s * 2048 + j0 + g2 * 8);
#pragma unroll
            for (int e = 0; e < 8; ++e) vT[sw_idx(j0 + g2 * 8 + e, s)] = vv[e];
        }
    }
    __syncthreads();

    bf16x8 bk[4][2];
#pragma unroll
    for (int nt = 0; nt < 4; ++nt) {
        bk[nt][0] = frag64(kT, nt * 16 + l15, quad);
        bk[nt][1] = frag64(kT, nt * 16 + l15, quad + 4);
    }
    fx4 acc[2][4];
#pragma unroll
    for (int mi = 0; mi < 2; ++mi)
#pragma unroll
        for (int nt = 0; nt < 4; ++nt) acc[mi][nt] = fx4{0.f, 0.f, 0.f, 0.f};
#pragma unroll
    for (int mi = 0; mi < 2; ++mi) {
        const int mrow = (w * 2 + mi) * 16 + l15;
        bf16x8 av0 = frag64(vT, mrow, quad);
        bf16x8 av1 = frag64(vT, mrow, quad + 4);
#pragma unroll
        for (int nt = 0; nt < 4; ++nt) {
            acc[mi][nt] = __builtin_amdgcn_mfma_f32_16x16x32_bf16(av0, bk[nt][0], acc[mi][nt], 0, 0, 0);
            acc[mi][nt] = __builtin_amdgcn_mfma_f32_16x16x32_bf16(av1, bk[nt][1], acc[mi][nt], 0, 0, 0);
        }
    }
    float* tb = Tc + (size_t)blk * 8192;
#pragma unroll
    for (int mi = 0; mi < 2; ++mi)
#pragma unroll
        for (int nt = 0; nt < 4; ++nt)
#pragma unroll
            for (int r = 0; r < 4; ++r) {
                const int j = (w * 2 + mi) * 16 + quad * 4 + r;
                const int d = nt * 16 + l15;
                tb[(size_t)j * 64 + d] = acc[mi][nt][r];
            }
}

// ---------------------------------------------------------------------------
// combine: 256 blocks, one fx4 chain per thread over the 32 chunks.
// TS holds T^T [j][d] fp32 on entry; on exit each 16B fx4 slot holds the
// PACKED bf16 {hi[4], lo[4]} of S_start (hi = f2b(S), lo = f2b(S - hi)).
// ---------------------------------------------------------------------------
__global__ __launch_bounds__(256) void combine_kernel(
    float* __restrict__ TS, const float* __restrict__ Ag)
{
    const int blk = blockIdx.x;       // bh*8 + js
    const int js = blk & 7, bh = blk >> 3;
    const int tid = threadIdx.x;
    const int j = js * 16 + (tid >> 4), d0 = (tid & 15) * 4;
    fx4 S = fx4{0.f, 0.f, 0.f, 0.f};
    const float* Abase = Ag + (size_t)bh * 2048 * 64;
    for (int c = 0; c < 32; ++c) {
        float* p = TS + ((size_t)(bh * 32 + c)) * 8192 + (size_t)j * 64 + d0;
        fx4 t = *(const fx4*)p;
        us8 pk;
#pragma unroll
        for (int e = 0; e < 4; ++e) {
            pk[e]     = f2b(S[e]);
            pk[4 + e] = f2b(S[e] - b2f(pk[e]));
        }
        *(us8*)p = pk;
        fx4 a = *(const fx4*)(Abase + ((size_t)c * 64 + 63) * 64 + d0);
#pragma unroll
        for (int e = 0; e < 4; ++e) S[e] = S[e] * __expf(a[e]) + t[e];
    }
}

// ---------------------------------------------------------------------------
// pass2 (MFMA): P = tri(Q~K~^T); O = Q~@S^T(hi/lo pre-packed) + P@V; LN;
// silu-gate; y.
// ---------------------------------------------------------------------------
__global__ __launch_bounds__(256) void pass2_kernel(
    const unsigned short* __restrict__ q, const unsigned short* __restrict__ k,
    int qkstr,
    const unsigned short* __restrict__ v, const float* __restrict__ Ag,
    const float* __restrict__ Sst, const unsigned short* __restrict__ sg,
    unsigned short* __restrict__ y)
{
    __shared__ __align__(16) unsigned short qs[64 * 64];    // q~ [t][d]
    __shared__ __align__(16) unsigned short ksh[64 * 64];   // k~ [s][d]
    __shared__ __align__(16) unsigned short vT[128 * 64];   // v^T [j][s]
    __shared__ __align__(16) unsigned short Pb[64 * 64];    // P [t][s] bf16
    __shared__ __align__(16) unsigned short Ob[64 * 144];   // normalized O [t][j]

    const int blk = blockIdx.x;
    const int ch = blk & 31, bh = blk >> 5;
    const int b = bh >> 4, h = bh & 15;
    const int tid = threadIdx.x;
    const int lane = tid & 63, w = tid >> 6;
    const int quad = lane >> 4, l15 = lane & 15;

    const float* Abase = Ag + ((size_t)bh * 2048 + ch * 64) * 64;
    const unsigned short* qbase = q + ((size_t)(b * 2048 + ch * 64)) * qkstr + h * 64;
    const unsigned short* kbase = k + ((size_t)(b * 2048 + ch * 64)) * qkstr + h * 64;
    const unsigned short* vbase = v + ((size_t)(b * 2048 + ch * 64)) * 2048 + h * 128;

    {
        const int t = tid >> 2, d0 = (tid & 3) * 16;
        float av[16];
        *(fx4*)(av)      = *(const fx4*)(Abase + (size_t)t * 64 + d0);
        *(fx4*)(av + 4)  = *(const fx4*)(Abase + (size_t)t * 64 + d0 + 4);
        *(fx4*)(av + 8)  = *(const fx4*)(Abase + (size_t)t * 64 + d0 + 8);
        *(fx4*)(av + 12) = *(const fx4*)(Abase + (size_t)t * 64 + d0 + 12);
        us8 q0 = *(const us8*)(qbase + (size_t)t * qkstr + d0);
        us8 q1 = *(const us8*)(qbase + (size_t)t * qkstr + d0 + 8);
        us8 k0 = *(const us8*)(kbase + (size_t)t * qkstr + d0);
        us8 k1 = *(const us8*)(kbase + (size_t)t * qkstr + d0 + 8);
        us8 qo0, qo1, ko0, ko1;
#pragma unroll
        for (int e = 0; e < 8; ++e) {
            float e0 = __expf(av[e]),     n0 = __expf(-av[e]);
            float e1 = __expf(av[8 + e]), n1 = __expf(-av[8 + e]);
            qo0[e] = f2b(b2f(q0[e]) * e0);
            qo1[e] = f2b(b2f(q1[e]) * e1);
            ko0[e] = f2b(b2f(k0[e]) * n0);
            ko1[e] = f2b(b2f(k1[e]) * n1);
        }
        const int c0 = d0 >> 3, t7 = t & 7;
        *(us8*)(qs  + t * 64 + ((c0 ^ t7) << 3))       = qo0;
        *(us8*)(qs  + t * 64 + (((c0 + 1) ^ t7) << 3)) = qo1;
        *(us8*)(ksh + t * 64 + ((c0 ^ t7) << 3))       = ko0;
        *(us8*)(ksh + t * 64 + (((c0 + 1) ^ t7) << 3)) = ko1;
    }
    {
        const int s = tid >> 2, j0 = (tid & 3) * 32;
#pragma unroll
        for (int g2 = 0; g2 < 4; ++g2) {
            us8 vv = *(const us8*)(vbase + (size_t)s * 2048 + j0 + g2 * 8);
#pragma unroll
            for (int e = 0; e < 8; ++e) vT[sw_idx(j0 + g2 * 8 + e, s)] = vv[e];
        }
    }
    __syncthreads();

    bf16x8 aQ0 = frag64(qs, w * 16 + l15, quad);
    bf16x8 aQ1 = frag64(qs, w * 16 + l15, quad + 4);
    fx4 accP[4];
#pragma unroll
    for (int nt = 0; nt < 4; ++nt) accP[nt] = fx4{0.f, 0.f, 0.f, 0.f};
#pragma unroll
    for (int nt = 0; nt < 4; ++nt) {
        bf16x8 bK0 = frag64(ksh, nt * 16 + l15, quad);
        bf16x8 bK1 = frag64(ksh, nt * 16 + l15, quad + 4);
        accP[nt] = __builtin_amdgcn_mfma_f32_16x16x32_bf16(aQ0, bK0, accP[nt], 0, 0, 0);
        accP[nt] = __builtin_amdgcn_mfma_f32_16x16x32_bf16(aQ1, bK1, accP[nt], 0, 0, 0);
    }
#pragma unroll
    for (int nt = 0; nt < 4; ++nt)
#pragma unroll
        for (int r = 0; r < 4; ++r) {
            const int t = w * 16 + quad * 4 + r;
            const int s = nt * 16 + l15;
            Pb[sw_idx(t, s)] = f2b((s <= t) ? accP[nt][r] : 0.0f);
        }
    __syncthreads();

    bf16x8 aP0 = frag64(Pb, w * 16 + l15, quad);
    bf16x8 aP1 = frag64(Pb, w * 16 + l15, quad + 4);
    const unsigned short* SP = (const unsigned short*)(Sst + (size_t)blk * 8192);
    fx4 accO[8];
#pragma unroll
    for (int nt = 0; nt < 8; ++nt) accO[nt] = fx4{0.f, 0.f, 0.f, 0.f};
#pragma unroll
    for (int nt = 0; nt < 8; ++nt) {
        const int j = nt * 16 + l15;
        bf16x8 bV0 = frag64(vT, j, quad);
        bf16x8 bV1 = frag64(vT, j, quad + 4);
        const unsigned short* sb = SP + (size_t)(j * 64 + quad * 8) * 2;
        us8 ga = *(const us8*)(sb);
        us8 gb = *(const us8*)(sb + 8);
        us8 gc = *(const us8*)(sb + 64);
        us8 gd = *(const us8*)(sb + 72);
        us8 hi0u = __builtin_shufflevector(ga, gb, 0, 1, 2, 3, 8, 9, 10, 11);
        us8 lo0u = __builtin_shufflevector(ga, gb, 4, 5, 6, 7, 12, 13, 14, 15);
        us8 hi1u = __builtin_shufflevector(gc, gd, 0, 1, 2, 3, 8, 9, 10, 11);
        us8 lo1u = __builtin_shufflevector(gc, gd, 4, 5, 6, 7, 12, 13, 14, 15);
        bf16x8 hi0 = __builtin_bit_cast(bf16x8, hi0u);
        bf16x8 lo0 = __builtin_bit_cast(bf16x8, lo0u);
        bf16x8 hi1 = __builtin_bit_cast(bf16x8, hi1u);
        bf16x8 lo1 = __builtin_bit_cast(bf16x8, lo1u);
        accO[nt] = __builtin_amdgcn_mfma_f32_16x16x32_bf16(aP0, bV0, accO[nt], 0, 0, 0);
        accO[nt] = __builtin_amdgcn_mfma_f32_16x16x32_bf16(aP1, bV1, accO[nt], 0, 0, 0);
        accO[nt] = __builtin_amdgcn_mfma_f32_16x16x32_bf16(aQ0, hi0, accO[nt], 0, 0, 0);
        accO[nt] = __builtin_amdgcn_mfma_f32_16x16x32_bf16(aQ1, hi1, accO[nt], 0, 0, 0);
        accO[nt] = __builtin_amdgcn_mfma_f32_16x16x32_bf16(aQ0, lo0, accO[nt], 0, 0, 0);
        accO[nt] = __builtin_amdgcn_mfma_f32_16x16x32_bf16(aQ1, lo1, accO[nt], 0, 0, 0);
    }

    float sum1[4] = {0.f, 0.f, 0.f, 0.f}, sum2[4] = {0.f, 0.f, 0.f, 0.f};
#pragma unroll
    for (int nt = 0; nt < 8; ++nt)
#pragma unroll
        for (int r = 0; r < 4; ++r) {
            float ov = accO[nt][r];
            sum1[r] += ov;
            sum2[r] += ov * ov;
        }
#pragma unroll
    for (int m = 1; m < 16; m <<= 1)
#pragma unroll
        for (int r = 0; r < 4; ++r) {
            sum1[r] += __shfl_xor(sum1[r], m, 64);
            sum2[r] += __shfl_xor(sum2[r], m, 64);
        }
    float mu[4], inv[4];
#pragma unroll
    for (int r = 0; r < 4; ++r) {
        mu[r] = sum1[r] * (1.0f / 128.0f);
        float var = sum2[r] * (1.0f / 128.0f) - mu[r] * mu[r];
        inv[r] = rsqrtf(var + 1e-5f);
    }
#pragma unroll
    for (int nt = 0; nt < 8; ++nt)
#pragma unroll
        for (int r = 0; r < 4; ++r) {
            const int t = w * 16 + quad * 4 + r;
            Ob[t * 144 + nt * 16 + l15] = f2b((accO[nt][r] - mu[r]) * inv[r]);
        }
    __syncthreads();

    {
        const int t2 = tid >> 2, jg = (tid & 3) * 32;
        const size_t obase = ((size_t)(b * 2048 + ch * 64 + t2)) * 2048 + h * 128 + jg;
#pragma unroll
        for (int g2 = 0; g2 < 4; ++g2) {
            us8 ob = *(const us8*)(Ob + t2 * 144 + jg + g2 * 8);
            us8 gv = *(const us8*)(sg + obase + g2 * 8);
            us8 ov;
#pragma unroll
            for (int e = 0; e < 8; ++e) ov[e] = f2b(b2f(gv[e]) * b2f(ob[e]));
            *(us8*)(y + obase + g2 * 8) = ov;
        }
    }
}

// ---------------------------------------------------------------------------
extern "C" void kernel_launch(void* const* d_in, const int* in_sizes, int n_in,
                              void* d_out, int out_size, void* d_ws, size_t ws_size,
                              hipStream_t stream)
{
    unsigned short* out = (unsigned short*)d_out;

    char* ws = (char*)d_ws;
    size_t off = 0;
    auto alloc = [&](size_t bytes) -> void* {
        void* p = ws + off;
        off += (bytes + 255) & ~(size_t)255;
        return p;
    };
    unsigned short* xb    = (unsigned short*)alloc((size_t)4096 * 2048 * 2);
    unsigned short* Wbig  = (unsigned short*)alloc((size_t)6144 * 2048 * 2); // [Wq;Wk;Wv;Wg]
    unsigned short* Wkg1b = (unsigned short*)alloc((size_t)16 * 2048 * 2);
    unsigned short* Wkg2b = (unsigned short*)alloc((size_t)1024 * 16 * 2);
    unsigned short* bkg2b = (unsigned short*)alloc((size_t)1024 * 2);
    unsigned short* bgb   = (unsigned short*)alloc((size_t)2048 * 2);
    unsigned short* Wob   = (unsigned short*)alloc((size_t)2048 * 2048 * 2);
    unsigned short* qkb  = (unsigned short*)alloc((size_t)4096 * 2048 * 2);  // q|k
    unsigned short* vb   = (unsigned short*)alloc((size_t)4096 * 2048 * 2);
    unsigned short* sgb  = (unsigned short*)alloc((size_t)4096 * 2048 * 2);
    unsigned short* yb   = (unsigned short*)alloc((size_t)4096 * 2048 * 2);
    float*          Agb  = (float*)alloc((size_t)4096 * 1024 * 4);
    float*          TS   = (float*)alloc((size_t)1024 * 8192 * 4);
    int*            flag = (int*)alloc(256);

    detect_kernel<<<1, 256, 0, stream>>>((const unsigned int*)d_in[0], flag);

    CvtArgs ca;
    ca.src[0] = d_in[0]; ca.dst[0] = xb;
    ca.src[1] = d_in[1]; ca.dst[1] = Wbig;                         // Wq
    ca.src[2] = d_in[2]; ca.dst[2] = Wbig + (size_t)1024 * 2048;   // Wk
    ca.src[3] = d_in[3]; ca.dst[3] = Wkg1b;
    ca.src[4] = d_in[4]; ca.dst[4] = Wkg2b;
    ca.src[5] = d_in[5]; ca.dst[5] = bkg2b;
    ca.src[6] = d_in[6]; ca.dst[6] = Wbig + (size_t)2048 * 2048;   // Wv
    ca.src[7] = d_in[7]; ca.dst[7] = Wbig + (size_t)4096 * 2048;   // Wg
    ca.src[8] = d_in[8]; ca.dst[8] = bgb;
    ca.src[9] = d_in[9]; ca.dst[9] = Wob;
    convert_all_kernel<<<24627, 256, 0, stream>>>(ca, flag);

    const float SCALE = 0.08838834764831845f;  // 128**-0.5

    Seg3 segs;
    segs.C0 = qkb; segs.C1 = vb; segs.C2 = sgb; segs.bias2 = bgb;
    // qk|v segments: 8-phase 256^2, grid 16x16 = 256 blocks = exactly 1 round
    gemm_fused3_kernel<<<dim3(16, 16), 512, 0, stream>>>(xb, Wbig, segs, SCALE);
    // g segment: m97-128^2, 512 blocks at 3/CU (all co-resident)
    gemm_g_kernel<<<dim3(16, 32), 256, 0, stream>>>(xb, Wbig, sgb, bgb);

    gate1_kernel<<<4096, 256, 0, stream>>>(xb, Wkg1b, Wkg2b, bkg2b, Agb);
    gate2_kernel<<<256, 256, 0, stream>>>(Agb);
    pass1_kernel<<<1024, 256, 0, stream>>>(qkb + 1024, 2048, vb, Agb, TS);
    combine_kernel<<<256, 256, 0, stream>>>(TS, Agb);
    pass2_kernel<<<1024, 256, 0, stream>>>(qkb, qkb + 1024, 2048, vb, Agb, TS, sgb, yb);
    gemm_bt_kernel<<<dim3(16, 32), 256, 0, stream>>>(yb, Wob, out, 4096, 2048, 2048, flag);
}